// Round 19
// baseline (71.869 us; speedup 1.0000x reference)
//
#include <hip/hip_runtime.h>
#include <hip/hip_bf16.h>

// Problem constants (match reference)
#define BATCH   8
#define CDIM    256
#define ODIM    16
#define GRID16  16
#define NCELL   4096            // 16*16*16
#define PADW    17
#define PADV    (PADW*PADW*PADW)
#define MAXK    32              // point chunks per batch (256 blocks total)
#define SENT16  0x007Fu         // mapped bf16 -inf
#define SENTPK  0x007F007Fu
#define TPB     1024            // 16 waves = 4/SIMD; arch cap 64 -> W-frags in LDS
#define NT      2               // M-tiles (16 pts each) per wave-iteration
#define NPAD    817             // padding words per (b, och) plane

// ws layout (u32 words):
//   [0, 2048)      : W2 bf16 MFMA A-fragments, u32x4 per (kt*64+lane)
//   [2048, 4096)   : W1 bf16 MFMA A-fragments, uint2 per (cg*64+lane)
//   [8192, ...)    : Km * BATCH slabs, G-MAJOR: u64[g][4096] per slab
#define HDR_WORDS   8192
#define SLAB_WORDS  (8 * 4096)   // 32768 u32 = 128 KiB

typedef __attribute__((ext_vector_type(8))) short bf16x8;
typedef __attribute__((ext_vector_type(4))) float f32x4;
typedef __attribute__((ext_vector_type(4))) unsigned u32x4;
typedef unsigned long long u64;

// ---------------------------------------------------------------------------
__device__ __forceinline__ float unmap16(unsigned m) {
    unsigned r = (m & 0x8000u) ? (m ^ 0x8000u) : (~m & 0xFFFFu);
    return __uint_as_float(r << 16);
}
__device__ __forceinline__ unsigned mpk(unsigned w) {
    return w ^ (0x80008000u | (((w >> 15) & 0x00010001u) * 0x7FFFu));
}
// two fp32 -> packed bf16 pair. INTRINSIC form (R19): the guide's m240 note
// says hand-written v_cvt_pk asm is an opaque scheduling barrier and loses
// ~37% vs letting the compiler emit the conversion -- this was instantiated
// ~200x per hot-loop iteration as asm through R9-R18.
__device__ __forceinline__ unsigned pkbf16(float lo, float hi) {
    __hip_bfloat162 p = __float22bfloat162_rn(make_float2(lo, hi));
    unsigned r;
    __builtin_memcpy(&r, &p, 4);
    return r;
}
__device__ __forceinline__ unsigned pmax(unsigned a, unsigned b) {
    unsigned hi = max(a >> 16, b >> 16);
    unsigned lo = max(a & 0xFFFFu, b & 0xFFFFu);
    return (hi << 16) | lo;
}
__device__ __forceinline__ u64 pmax64(u64 a, u64 b) {
    unsigned lo = pmax((unsigned)a, (unsigned)b);
    unsigned hi = pmax((unsigned)(a >> 32), (unsigned)(b >> 32));
    return ((u64)hi << 32) | lo;
}

// ---------------------------------------------------------------------------
// Pack W2 (u32x4) and W1 (uint2) MFMA A-fragments.
// k-map c(kt,j,g) = kt*32 + (j>>2)*16 + 4g + (j&3).
__global__ void k_pack2(const float* __restrict__ W1, const float* __restrict__ b1,
                        const float* __restrict__ W2, unsigned* __restrict__ ws) {
    int t = threadIdx.x;                    // 1024 threads
    if (t < 512) {
        int kt = t >> 6, l = t & 63;
        int g = (l >> 4), o = l & 15;
        const float* wr = W2 + o * CDIM + kt * 32 + 4 * g;
        uint4 q;
        q.x = pkbf16(wr[0],  wr[1]);
        q.y = pkbf16(wr[2],  wr[3]);
        q.z = pkbf16(wr[16], wr[17]);
        q.w = pkbf16(wr[18], wr[19]);
        reinterpret_cast<uint4*>(ws)[t] = q;
    }
    {
        int cg = t >> 6, l = t & 63;
        int lp = l & 15, g = l >> 4;
        int c = cg * 16 + lp;
        uint2 q = {0u, 0u};
        if (g == 0) {
            q.x = pkbf16(W1[c * 3 + 0], W1[c * 3 + 1]);
            q.y = pkbf16(W1[c * 3 + 2], b1[c]);
        }
        reinterpret_cast<uint2*>(ws + 2048)[t] = q;
    }
}

// ---------------------------------------------------------------------------
__device__ __forceinline__ void casmax64(u64* addr, u64 wv) {
    u64 cur = *addr;
    while (true) {
        u64 nv = pmax64(cur, wv);
        if (nv == cur) return;
        u64 prev = atomicCAS(addr, cur, nv);
        if (prev == cur) return;
        cur = prev;
    }
}

__device__ __forceinline__ bf16x8 mk_frag(unsigned w0, unsigned w1) {
    u32x4 u = {w0, w1, 0u, 0u};
    return __builtin_bit_cast(bf16x8, u);
}

// ---------------------------------------------------------------------------
// MFMA scatter: block (k, b). 16 waves (4/SIMD); NT=2 16-pt M-tiles/iter.
//   L1: h[ch16][pt16]  = W1(A, LDS b64 frag) * x(B)
//   L2: D[och16][pt16] = W2(A, LDS b128 frag) * h(B) + b2(C-in)
// R19: identical to R18 except pkbf16 asm -> intrinsic (see above).
__global__ __launch_bounds__(TPB, 1)
void k_scatter_mfma(const float* __restrict__ xin,
                    const unsigned* __restrict__ ws,
                    const float* __restrict__ b2,
                    unsigned* __restrict__ slabs,
                    int nper, int chunk) {
    __shared__ u64 cm64[SLAB_WORDS / 2];     // 128 KiB; [g][4096] u64
    __shared__ uint2 w1fs[1024];             // 8 KiB
    __shared__ u32x4 w2fs[512];              // 8 KiB
    unsigned* cm = reinterpret_cast<unsigned*>(cm64);
    const int kblk = blockIdx.x, b = blockIdx.z;
    const int tid = threadIdx.x;
    const int l = tid & 63, wv = tid >> 6;   // lane, wave (0..15)
    const int g = l >> 4;                    // lane group 0..3
    const bool g0 = (g == 0);
    const int lp = l & 15;                   // point slot within tile

    w1fs[tid] = reinterpret_cast<const uint2*>(ws + 2048)[tid];
    if (tid < 512)
        w2fs[tid] = reinterpret_cast<const u32x4*>(ws)[tid];
    {   // sentinel init
        u32x4 s = {SENTPK, SENTPK, SENTPK, SENTPK};
        u32x4* cm4 = reinterpret_cast<u32x4*>(cm);
        for (int i = tid; i < SLAB_WORDS / 4; i += TPB) cm4[i] = s;
    }
    float4 b4 = reinterpret_cast<const float4*>(b2)[g];
    const f32x4 bb = {b4.x, b4.y, b4.z, b4.w};
    const f32x4 z4 = {0.f, 0.f, 0.f, 0.f};
    __syncthreads();

    const int p0 = kblk * chunk;
    const int p1 = min(p0 + chunk, nper);
    const float* xb = xin + (size_t)b * nper * 3;
    const int STRIDE = (TPB / 64) * NT * 16; // 512 points per block-iter

    float cx[NT], cy[NT], cz[NT];
#pragma unroll
    for (int t = 0; t < NT; ++t) {
        int p = min(p0 + wv * (NT * 16) + t * 16 + lp, nper - 1);
        cx[t] = xb[p * 3 + 0]; cy[t] = xb[p * 3 + 1]; cz[t] = xb[p * 3 + 2];
    }

    for (int gb = p0 + wv * (NT * 16); gb < p1; gb += STRIDE) {
        // issue next-iter x loads early (clamped, branchless)
        float nx[NT], ny[NT], nz[NT];
#pragma unroll
        for (int t = 0; t < NT; ++t) {
            int p = min(gb + STRIDE + t * 16 + lp, nper - 1);
            nx[t] = xb[p * 3 + 0]; ny[t] = xb[p * 3 + 1]; nz[t] = xb[p * 3 + 2];
        }

        int cell16[NT];
        bf16x8 bx[NT];
#pragma unroll
        for (int t = 0; t < NT; ++t) {
            cell16[t] = ((min(max((int)floorf(cx[t]), 0), 15) << 8) |
                         (min(max((int)floorf(cy[t]), 0), 15) << 4) |
                          min(max((int)floorf(cz[t]), 0), 15));
            bx[t] = mk_frag(g0 ? pkbf16(cx[t], cy[t]) : 0u,
                            g0 ? pkbf16(cz[t], 1.0f) : 0u);
        }

        f32x4 acc[NT];
#pragma unroll
        for (int t = 0; t < NT; ++t) acc[t] = bb;

#pragma unroll
        for (int kt = 0; kt < 8; ++kt) {
            uint2 a0 = w1fs[(2 * kt) * 64 + l];
            uint2 a1 = w1fs[(2 * kt + 1) * 64 + l];
            u32x4 wq = w2fs[kt * 64 + l];
            bf16x8 w1a = mk_frag(a0.x, a0.y);
            bf16x8 w1b = mk_frag(a1.x, a1.y);
            bf16x8 w2a = __builtin_bit_cast(bf16x8, wq);
#pragma unroll
            for (int t = 0; t < NT; ++t) {
                f32x4 h0 = __builtin_amdgcn_mfma_f32_16x16x32_bf16(w1a, bx[t], z4, 0, 0, 0);
                f32x4 h1 = __builtin_amdgcn_mfma_f32_16x16x32_bf16(w1b, bx[t], z4, 0, 0, 0);
                u32x4 ua;
                ua[0] = pkbf16(fmaxf(h0[0],0.f), fmaxf(h0[1],0.f));
                ua[1] = pkbf16(fmaxf(h0[2],0.f), fmaxf(h0[3],0.f));
                ua[2] = pkbf16(fmaxf(h1[0],0.f), fmaxf(h1[1],0.f));
                ua[3] = pkbf16(fmaxf(h1[2],0.f), fmaxf(h1[3],0.f));
                acc[t] = __builtin_amdgcn_mfma_f32_16x16x32_bf16(
                             w2a, __builtin_bit_cast(bf16x8, ua), acc[t], 0, 0, 0);
            }
        }

        // epilogue per tile: in-lane, ONE u64 casmax per lane (g-major grid)
#pragma unroll
        for (int t = 0; t < NT; ++t) {
            if (gb + t * 16 + lp < p1) {
                unsigned w01 = mpk(pkbf16(acc[t][0], acc[t][1]));
                unsigned w23 = mpk(pkbf16(acc[t][2], acc[t][3]));
                u64 wq = ((u64)w23 << 32) | w01;
                casmax64(&cm64[(g << 12) + cell16[t]], wq);
            }
        }

#pragma unroll
        for (int t = 0; t < NT; ++t) { cx[t] = nx[t]; cy[t] = ny[t]; cz[t] = nz[t]; }
    }
    __syncthreads();

    // flush slab (flat copy; layout preserved)
    unsigned* dst = slabs + (size_t)(kblk * BATCH + b) * SLAB_WORDS;
    uint4* d4 = reinterpret_cast<uint4*>(dst);
    const uint4* s4 = reinterpret_cast<const uint4*>(cm);
    for (int i = tid; i < SLAB_WORDS / 4; i += TPB) d4[i] = s4[i];
}

// ---------------------------------------------------------------------------
// reduce K slabs -> out interior; extra threads write the zero padding.
// G-major slab: word = g*8192 + cell*2 + w; channels 4g+2w, 4g+2w+1.
__global__ __launch_bounds__(256)
void k_reduce4(const unsigned* __restrict__ slabs, float* __restrict__ out, int K) {
    int t = blockIdx.x * 256 + threadIdx.x;
    if (t < BATCH * NCELL) {
        int cell = t & (NCELL - 1), b = t >> 12;

        unsigned m[8];
#pragma unroll
        for (int i = 0; i < 8; ++i) m[i] = SENTPK;

        for (int k = 0; k < K; ++k) {
            const unsigned* s = slabs + (size_t)(k * BATCH + b) * SLAB_WORDS + cell * 2;
#pragma unroll
            for (int g = 0; g < 4; ++g) {
                uint2 a = *reinterpret_cast<const uint2*>(s + g * 8192);
                m[2*g]     = pmax(m[2*g],     a.x);
                m[2*g + 1] = pmax(m[2*g + 1], a.y);
            }
        }

        int ix = cell >> 8, iy = (cell >> 4) & 15, iz = cell & 15;
        size_t obase = ((size_t)b * ODIM) * PADV + ((ix * PADW + iy) * PADW + iz);
#pragma unroll
        for (int op = 0; op < 8; ++op) {
            unsigned lo = m[op] & 0xFFFFu, hi = m[op] >> 16;
            out[obase + (size_t)(2 * op)     * PADV] = (lo == SENT16) ? 0.0f : unmap16(lo);
            out[obase + (size_t)(2 * op + 1) * PADV] = (hi == SENT16) ? 0.0f : unmap16(hi);
        }
    } else {
        // padding writer: one thread per padding word
        int pt = t - BATCH * NCELL;
        if (pt >= BATCH * ODIM * NPAD) return;
        int bo = pt / NPAD;                 // (b*ODIM + och), 0..127
        int r  = pt - bo * NPAD;
        int x, y, z;
        if (r < 289)      { x = 16; y = r / 17; z = r - (r / 17) * 17; }
        else if (r < 561) { int r2 = r - 289; x = r2 / 17; y = 16; z = r2 - (r2 / 17) * 17; }
        else              { int r3 = r - 561; x = r3 >> 4; y = r3 & 15; z = 16; }
        out[(size_t)bo * PADV + (x * PADW + y) * PADW + z] = 0.0f;
    }
}

// ===========================================================================
// Fallback (round-1): direct global atomics. Used only if ws too small.
__global__ void k_init(unsigned* __restrict__ out, int total) {
    int i = blockIdx.x * blockDim.x + threadIdx.x;
    if (i >= total) return;
    int r = i % PADV;
    int z = r % PADW, y = (r / PADW) % PADW, x = r / (PADW * PADW);
    out[i] = (x < GRID16 && y < GRID16 && z < GRID16) ? 0xFF800000u : 0u;
}
__device__ __forceinline__ void atomicMaxFloat(float* addr, float v) {
    if (v >= 0.0f) atomicMax(reinterpret_cast<int*>(addr), __float_as_int(v));
    else           atomicMin(reinterpret_cast<unsigned*>(addr), __float_as_uint(v));
}
__global__ __launch_bounds__(256)
void k_scatter_glb(const float* __restrict__ xin,
                   const float* __restrict__ W1, const float* __restrict__ b1,
                   const float* __restrict__ W2, const float* __restrict__ b2,
                   float* __restrict__ out, int npts, int nper) {
    int p = blockIdx.x * 256 + threadIdx.x;
    if (p >= npts) return;
    float x0 = xin[p*3+0], x1 = xin[p*3+1], x2 = xin[p*3+2];
    float acc[ODIM];
#pragma unroll
    for (int o = 0; o < ODIM; ++o) acc[o] = b2[o];
#pragma unroll 2
    for (int c = 0; c < CDIM; ++c) {
        float h = fmaf(W1[c*3+0], x0, fmaf(W1[c*3+1], x1, fmaf(W1[c*3+2], x2, b1[c])));
        h = fmaxf(h, 0.0f);
#pragma unroll
        for (int o = 0; o < ODIM; ++o) acc[o] = fmaf(W2[o*CDIM+c], h, acc[o]);
    }
    int ix = min(max((int)floorf(x0), 0), GRID16-1);
    int iy = min(max((int)floorf(x1), 0), GRID16-1);
    int iz = min(max((int)floorf(x2), 0), GRID16-1);
    int b = p / nper;
    size_t base = ((((size_t)b*ODIM)*PADW + ix)*PADW + iy)*PADW + iz;
#pragma unroll
    for (int o = 0; o < ODIM; ++o)
        atomicMaxFloat(out + base + (size_t)o*PADV, acc[o]);
}
__global__ void k_final(unsigned* __restrict__ out, int total) {
    int i = blockIdx.x * blockDim.x + threadIdx.x;
    if (i >= total) return;
    if (out[i] == 0xFF800000u) out[i] = 0u;
}

// ===========================================================================
extern "C" void kernel_launch(void* const* d_in, const int* in_sizes, int n_in,
                              void* d_out, int out_size, void* d_ws, size_t ws_size,
                              hipStream_t stream) {
    const float* x  = (const float*)d_in[0];
    const float* W1 = (const float*)d_in[1];
    const float* b1 = (const float*)d_in[2];
    const float* W2 = (const float*)d_in[3];
    const float* b2 = (const float*)d_in[4];
    float* out = (float*)d_out;

    int npts = in_sizes[0] / 3;          // B*N
    int nper = npts / BATCH;             // N

    size_t ws_words = ws_size / 4;
    int Km = 0;
    if (ws_words > HDR_WORDS) {
        size_t avail = (ws_words - HDR_WORDS) / ((size_t)BATCH * SLAB_WORDS);
        Km = (int)min((size_t)MAXK, avail);
    }

    if (Km >= 1) {
        unsigned* ws = (unsigned*)d_ws;
        k_pack2<<<1, 1024, 0, stream>>>(W1, b1, W2, ws);

        unsigned* slabs = ws + HDR_WORDS;
        int chunk = (nper + Km - 1) / Km;
        dim3 grid(Km, 1, BATCH);
        k_scatter_mfma<<<grid, TPB, 0, stream>>>(x, ws, b2, slabs, nper, chunk);

        int rt = BATCH * NCELL + BATCH * ODIM * NPAD;  // interior + padding
        k_reduce4<<<(rt + 255) / 256, 256, 0, stream>>>(slabs, out, Km);
    } else {
        int total = out_size;
        k_init<<<(total + 255) / 256, 256, 0, stream>>>((unsigned*)out, total);
        int blocks = (npts + 255) / 256;
        k_scatter_glb<<<blocks, 256, 0, stream>>>(x, W1, b1, W2, b2, out, npts, nper);
        k_final<<<(total + 255) / 256, 256, 0, stream>>>((unsigned*)out, total);
    }
}

// Round 20
// 64.126 us; speedup vs baseline: 1.1208x; 1.1208x over previous
//
#include <hip/hip_runtime.h>
#include <hip/hip_bf16.h>

// Problem constants (match reference)
#define BATCH   8
#define CDIM    256
#define ODIM    16
#define GRID16  16
#define NCELL   4096            // 16*16*16
#define PADW    17
#define PADV    (PADW*PADW*PADW)
#define MAXK    32              // point chunks per batch (256 blocks total)
#define SENT16  0x007Fu         // mapped bf16 -inf
#define SENTPK  0x007F007Fu
#define TPB     1024            // 16 waves = 4/SIMD; arch cap 64 -> W-frags in LDS
#define NT      2               // M-tiles (16 pts each) per wave-iteration
#define NPAD    817             // padding words per (b, och) plane

// ws layout (u32 words):
//   [0, 2048)      : W2 bf16 MFMA A-fragments, u32x4 per (kt*64+lane)
//   [2048, 6144)   : W1 bf16 MFMA A-fragments, u32x4 per (cg*64+lane)
//   [8192, ...)    : Km * BATCH slabs, G-MAJOR: u64[g][4096] per slab
#define HDR_WORDS   8192
#define SLAB_WORDS  (8 * 4096)   // 32768 u32 = 128 KiB

typedef __attribute__((ext_vector_type(8))) short bf16x8;
typedef __attribute__((ext_vector_type(4))) float f32x4;
typedef __attribute__((ext_vector_type(4))) unsigned u32x4;
typedef unsigned long long u64;

// ---------------------------------------------------------------------------
__device__ __forceinline__ float unmap16(unsigned m) {
    unsigned r = (m & 0x8000u) ? (m ^ 0x8000u) : (~m & 0xFFFFu);
    return __uint_as_float(r << 16);
}
__device__ __forceinline__ unsigned mpk(unsigned w) {
    return w ^ (0x80008000u | (((w >> 15) & 0x00010001u) * 0x7FFFu));
}
// two fp32 -> packed bf16 pair. ASM form: R19 proved the intrinsic version
// inflates the live set past the 64-arch cap at 4 waves/SIMD (spill returned,
// FETCH 5.5->20MB); the single-instruction asm is optimal here.
__device__ __forceinline__ unsigned pkbf16(float lo, float hi) {
    unsigned r;
    asm("v_cvt_pk_bf16_f32 %0, %1, %2" : "=v"(r) : "v"(lo), "v"(hi));
    return r;
}
__device__ __forceinline__ unsigned pmax(unsigned a, unsigned b) {
    unsigned hi = max(a >> 16, b >> 16);
    unsigned lo = max(a & 0xFFFFu, b & 0xFFFFu);
    return (hi << 16) | lo;
}
__device__ __forceinline__ u64 pmax64(u64 a, u64 b) {
    unsigned lo = pmax((unsigned)a, (unsigned)b);
    unsigned hi = pmax((unsigned)(a >> 32), (unsigned)(b >> 32));
    return ((u64)hi << 32) | lo;
}

// ---------------------------------------------------------------------------
// Pack W2 and W1 MFMA A-fragments (both u32x4 per (idx*64+lane)).
// k-map c(kt,j,g) = kt*32 + (j>>2)*16 + 4g + (j&3).
__global__ void k_pack2(const float* __restrict__ W1, const float* __restrict__ b1,
                        const float* __restrict__ W2, unsigned* __restrict__ ws) {
    int t = threadIdx.x;                    // 1024 threads
    if (t < 512) {
        int kt = t >> 6, l = t & 63;
        int g = (l >> 4), o = l & 15;
        const float* wr = W2 + o * CDIM + kt * 32 + 4 * g;
        uint4 q;
        q.x = pkbf16(wr[0],  wr[1]);
        q.y = pkbf16(wr[2],  wr[3]);
        q.z = pkbf16(wr[16], wr[17]);
        q.w = pkbf16(wr[18], wr[19]);
        reinterpret_cast<uint4*>(ws)[t] = q;
    }
    // W1 A-fragment item t: cg = t>>6, lane l = t&63 (g>0 lanes zero; K=4/32)
    {
        int cg = t >> 6, l = t & 63;
        int lp = l & 15, g = l >> 4;
        int c = cg * 16 + lp;
        uint4 q = {0u, 0u, 0u, 0u};
        if (g == 0) {
            q.x = pkbf16(W1[c * 3 + 0], W1[c * 3 + 1]);
            q.y = pkbf16(W1[c * 3 + 2], b1[c]);
        }
        reinterpret_cast<uint4*>(ws + 2048)[t] = q;
    }
}

// ---------------------------------------------------------------------------
__device__ __forceinline__ void casmax64(u64* addr, u64 wv) {
    u64 cur = *addr;
    while (true) {
        u64 nv = pmax64(cur, wv);
        if (nv == cur) return;
        u64 prev = atomicCAS(addr, cur, nv);
        if (prev == cur) return;
        cur = prev;
    }
}

__device__ __forceinline__ bf16x8 mk_frag(unsigned w0, unsigned w1) {
    u32x4 u = {w0, w1, 0u, 0u};
    return __builtin_bit_cast(bf16x8, u);
}

// ---------------------------------------------------------------------------
// MFMA scatter: block (k, b). 16 waves (4/SIMD); NT=2 16-pt M-tiles/iter.
//   L1: h[ch16][pt16]  = W1(A, LDS b128 frag) * x(B)
//   L2: D[och16][pt16] = W2(A, LDS b128 frag) * h(B) + b2(C-in)
// R20 = best-of recombination (final): R17's u32x4 W1 frags + asm pkbf16
// (fastest measured scatter, 46.0us) + R18's fused pad-writer reduce.
// Structural floor: all pipes <50% busy; TLP/ILP/atomic/DS/bank levers all
// measured null R11-R19 -- latency-bound MFMA->pack->MFMA->CAS chain.
__global__ __launch_bounds__(TPB, 1)
void k_scatter_mfma(const float* __restrict__ xin,
                    const unsigned* __restrict__ ws,
                    const float* __restrict__ b2,
                    unsigned* __restrict__ slabs,
                    int nper, int chunk) {
    __shared__ u64 cm64[SLAB_WORDS / 2];     // 128 KiB; [g][4096] u64
    __shared__ u32x4 w1fs[1024];             // 16 KiB
    __shared__ u32x4 w2fs[512];              // 8 KiB
    unsigned* cm = reinterpret_cast<unsigned*>(cm64);
    const int kblk = blockIdx.x, b = blockIdx.z;
    const int tid = threadIdx.x;
    const int l = tid & 63, wv = tid >> 6;   // lane, wave (0..15)
    const int g = l >> 4;                    // lane group 0..3
    const bool g0 = (g == 0);
    const int lp = l & 15;                   // point slot within tile

    w1fs[tid] = reinterpret_cast<const u32x4*>(ws + 2048)[tid];
    if (tid < 512)
        w2fs[tid] = reinterpret_cast<const u32x4*>(ws)[tid];
    {   // sentinel init: 8192 uint4 / 1024 threads
        u32x4 s = {SENTPK, SENTPK, SENTPK, SENTPK};
        u32x4* cm4 = reinterpret_cast<u32x4*>(cm);
        for (int i = tid; i < SLAB_WORDS / 4; i += TPB) cm4[i] = s;
    }
    float4 b4 = reinterpret_cast<const float4*>(b2)[g];
    const f32x4 bb = {b4.x, b4.y, b4.z, b4.w};
    const f32x4 z4 = {0.f, 0.f, 0.f, 0.f};
    __syncthreads();

    const int p0 = kblk * chunk;
    const int p1 = min(p0 + chunk, nper);
    const float* xb = xin + (size_t)b * nper * 3;
    const int STRIDE = (TPB / 64) * NT * 16; // 512 points per block-iter

    float cx[NT], cy[NT], cz[NT];
#pragma unroll
    for (int t = 0; t < NT; ++t) {
        int p = min(p0 + wv * (NT * 16) + t * 16 + lp, nper - 1);
        cx[t] = xb[p * 3 + 0]; cy[t] = xb[p * 3 + 1]; cz[t] = xb[p * 3 + 2];
    }

    for (int gb = p0 + wv * (NT * 16); gb < p1; gb += STRIDE) {
        // issue next-iter x loads early (clamped, branchless)
        float nx[NT], ny[NT], nz[NT];
#pragma unroll
        for (int t = 0; t < NT; ++t) {
            int p = min(gb + STRIDE + t * 16 + lp, nper - 1);
            nx[t] = xb[p * 3 + 0]; ny[t] = xb[p * 3 + 1]; nz[t] = xb[p * 3 + 2];
        }

        int cell16[NT];
        bf16x8 bx[NT];
#pragma unroll
        for (int t = 0; t < NT; ++t) {
            cell16[t] = ((min(max((int)floorf(cx[t]), 0), 15) << 8) |
                         (min(max((int)floorf(cy[t]), 0), 15) << 4) |
                          min(max((int)floorf(cz[t]), 0), 15));
            bx[t] = mk_frag(g0 ? pkbf16(cx[t], cy[t]) : 0u,
                            g0 ? pkbf16(cz[t], 1.0f) : 0u);
        }

        f32x4 acc[NT];
#pragma unroll
        for (int t = 0; t < NT; ++t) acc[t] = bb;

#pragma unroll
        for (int kt = 0; kt < 8; ++kt) {
            u32x4 a0 = w1fs[(2 * kt) * 64 + l];      // ds_read_b128
            u32x4 a1 = w1fs[(2 * kt + 1) * 64 + l];
            u32x4 wq = w2fs[kt * 64 + l];
            bf16x8 w1a = __builtin_bit_cast(bf16x8, a0);
            bf16x8 w1b = __builtin_bit_cast(bf16x8, a1);
            bf16x8 w2a = __builtin_bit_cast(bf16x8, wq);
#pragma unroll
            for (int t = 0; t < NT; ++t) {
                f32x4 h0 = __builtin_amdgcn_mfma_f32_16x16x32_bf16(w1a, bx[t], z4, 0, 0, 0);
                f32x4 h1 = __builtin_amdgcn_mfma_f32_16x16x32_bf16(w1b, bx[t], z4, 0, 0, 0);
                u32x4 ua;
                ua[0] = pkbf16(fmaxf(h0[0],0.f), fmaxf(h0[1],0.f));
                ua[1] = pkbf16(fmaxf(h0[2],0.f), fmaxf(h0[3],0.f));
                ua[2] = pkbf16(fmaxf(h1[0],0.f), fmaxf(h1[1],0.f));
                ua[3] = pkbf16(fmaxf(h1[2],0.f), fmaxf(h1[3],0.f));
                acc[t] = __builtin_amdgcn_mfma_f32_16x16x32_bf16(
                             w2a, __builtin_bit_cast(bf16x8, ua), acc[t], 0, 0, 0);
            }
        }

        // epilogue per tile: in-lane, ONE u64 casmax per lane (g-major grid)
#pragma unroll
        for (int t = 0; t < NT; ++t) {
            if (gb + t * 16 + lp < p1) {
                unsigned w01 = mpk(pkbf16(acc[t][0], acc[t][1]));
                unsigned w23 = mpk(pkbf16(acc[t][2], acc[t][3]));
                u64 wq = ((u64)w23 << 32) | w01;
                casmax64(&cm64[(g << 12) + cell16[t]], wq);
            }
        }

#pragma unroll
        for (int t = 0; t < NT; ++t) { cx[t] = nx[t]; cy[t] = ny[t]; cz[t] = nz[t]; }
    }
    __syncthreads();

    // flush slab (flat copy; layout preserved)
    unsigned* dst = slabs + (size_t)(kblk * BATCH + b) * SLAB_WORDS;
    uint4* d4 = reinterpret_cast<uint4*>(dst);
    const uint4* s4 = reinterpret_cast<const uint4*>(cm);
    for (int i = tid; i < SLAB_WORDS / 4; i += TPB) d4[i] = s4[i];
}

// ---------------------------------------------------------------------------
// reduce K slabs -> out interior; extra threads write the zero padding.
// G-major slab: word = g*8192 + cell*2 + w; channels 4g+2w, 4g+2w+1.
__global__ __launch_bounds__(256)
void k_reduce4(const unsigned* __restrict__ slabs, float* __restrict__ out, int K) {
    int t = blockIdx.x * 256 + threadIdx.x;
    if (t < BATCH * NCELL) {
        int cell = t & (NCELL - 1), b = t >> 12;

        unsigned m[8];
#pragma unroll
        for (int i = 0; i < 8; ++i) m[i] = SENTPK;

        for (int k = 0; k < K; ++k) {
            const unsigned* s = slabs + (size_t)(k * BATCH + b) * SLAB_WORDS + cell * 2;
#pragma unroll
            for (int g = 0; g < 4; ++g) {
                uint2 a = *reinterpret_cast<const uint2*>(s + g * 8192);
                m[2*g]     = pmax(m[2*g],     a.x);
                m[2*g + 1] = pmax(m[2*g + 1], a.y);
            }
        }

        int ix = cell >> 8, iy = (cell >> 4) & 15, iz = cell & 15;
        size_t obase = ((size_t)b * ODIM) * PADV + ((ix * PADW + iy) * PADW + iz);
#pragma unroll
        for (int op = 0; op < 8; ++op) {
            unsigned lo = m[op] & 0xFFFFu, hi = m[op] >> 16;
            out[obase + (size_t)(2 * op)     * PADV] = (lo == SENT16) ? 0.0f : unmap16(lo);
            out[obase + (size_t)(2 * op + 1) * PADV] = (hi == SENT16) ? 0.0f : unmap16(hi);
        }
    } else {
        // padding writer: one thread per padding word
        int pt = t - BATCH * NCELL;
        if (pt >= BATCH * ODIM * NPAD) return;
        int bo = pt / NPAD;                 // (b*ODIM + och), 0..127
        int r  = pt - bo * NPAD;
        int x, y, z;
        if (r < 289)      { x = 16; y = r / 17; z = r - (r / 17) * 17; }
        else if (r < 561) { int r2 = r - 289; x = r2 / 17; y = 16; z = r2 - (r2 / 17) * 17; }
        else              { int r3 = r - 561; x = r3 >> 4; y = r3 & 15; z = 16; }
        out[(size_t)bo * PADV + (x * PADW + y) * PADW + z] = 0.0f;
    }
}

// ===========================================================================
// Fallback (round-1): direct global atomics. Used only if ws too small.
__global__ void k_init(unsigned* __restrict__ out, int total) {
    int i = blockIdx.x * blockDim.x + threadIdx.x;
    if (i >= total) return;
    int r = i % PADV;
    int z = r % PADW, y = (r / PADW) % PADW, x = r / (PADW * PADW);
    out[i] = (x < GRID16 && y < GRID16 && z < GRID16) ? 0xFF800000u : 0u;
}
__device__ __forceinline__ void atomicMaxFloat(float* addr, float v) {
    if (v >= 0.0f) atomicMax(reinterpret_cast<int*>(addr), __float_as_int(v));
    else           atomicMin(reinterpret_cast<unsigned*>(addr), __float_as_uint(v));
}
__global__ __launch_bounds__(256)
void k_scatter_glb(const float* __restrict__ xin,
                   const float* __restrict__ W1, const float* __restrict__ b1,
                   const float* __restrict__ W2, const float* __restrict__ b2,
                   float* __restrict__ out, int npts, int nper) {
    int p = blockIdx.x * 256 + threadIdx.x;
    if (p >= npts) return;
    float x0 = xin[p*3+0], x1 = xin[p*3+1], x2 = xin[p*3+2];
    float acc[ODIM];
#pragma unroll
    for (int o = 0; o < ODIM; ++o) acc[o] = b2[o];
#pragma unroll 2
    for (int c = 0; c < CDIM; ++c) {
        float h = fmaf(W1[c*3+0], x0, fmaf(W1[c*3+1], x1, fmaf(W1[c*3+2], x2, b1[c])));
        h = fmaxf(h, 0.0f);
#pragma unroll
        for (int o = 0; o < ODIM; ++o) acc[o] = fmaf(W2[o*CDIM+c], h, acc[o]);
    }
    int ix = min(max((int)floorf(x0), 0), GRID16-1);
    int iy = min(max((int)floorf(x1), 0), GRID16-1);
    int iz = min(max((int)floorf(x2), 0), GRID16-1);
    int b = p / nper;
    size_t base = ((((size_t)b*ODIM)*PADW + ix)*PADW + iy)*PADW + iz;
#pragma unroll
    for (int o = 0; o < ODIM; ++o)
        atomicMaxFloat(out + base + (size_t)o*PADV, acc[o]);
}
__global__ void k_final(unsigned* __restrict__ out, int total) {
    int i = blockIdx.x * blockDim.x + threadIdx.x;
    if (i >= total) return;
    if (out[i] == 0xFF800000u) out[i] = 0u;
}

// ===========================================================================
extern "C" void kernel_launch(void* const* d_in, const int* in_sizes, int n_in,
                              void* d_out, int out_size, void* d_ws, size_t ws_size,
                              hipStream_t stream) {
    const float* x  = (const float*)d_in[0];
    const float* W1 = (const float*)d_in[1];
    const float* b1 = (const float*)d_in[2];
    const float* W2 = (const float*)d_in[3];
    const float* b2 = (const float*)d_in[4];
    float* out = (float*)d_out;

    int npts = in_sizes[0] / 3;          // B*N
    int nper = npts / BATCH;             // N

    size_t ws_words = ws_size / 4;
    int Km = 0;
    if (ws_words > HDR_WORDS) {
        size_t avail = (ws_words - HDR_WORDS) / ((size_t)BATCH * SLAB_WORDS);
        Km = (int)min((size_t)MAXK, avail);
    }

    if (Km >= 1) {
        unsigned* ws = (unsigned*)d_ws;
        k_pack2<<<1, 1024, 0, stream>>>(W1, b1, W2, ws);

        unsigned* slabs = ws + HDR_WORDS;
        int chunk = (nper + Km - 1) / Km;
        dim3 grid(Km, 1, BATCH);
        k_scatter_mfma<<<grid, TPB, 0, stream>>>(x, ws, b2, slabs, nper, chunk);

        int rt = BATCH * NCELL + BATCH * ODIM * NPAD;  // interior + padding
        k_reduce4<<<(rt + 255) / 256, 256, 0, stream>>>(slabs, out, Km);
    } else {
        int total = out_size;
        k_init<<<(total + 255) / 256, 256, 0, stream>>>((unsigned*)out, total);
        int blocks = (npts + 255) / 256;
        k_scatter_glb<<<blocks, 256, 0, stream>>>(x, W1, b1, W2, b2, out, npts, nper);
        k_final<<<(total + 255) / 256, 256, 0, stream>>>((unsigned*)out, total);
    }
}